// Round 9
// baseline (213.495 us; speedup 1.0000x reference)
//
#include <hip/hip_runtime.h>

// Blur = separable 4-tap FIR, taps [0.25,0.75,0.75,0.25], zero-pad (2,1)/(2,1).
// Plane-per-wave: each wave owns one full (n,c) 256x256 plane -> every input
// row is loaded EXACTLY once (no strip halo re-reads; pad rows synthesized as
// zeros). Deferred-store pipeline (consume -> refill loads -> stores) keeps
// waited-on loads older than in-flight stores; full non-temporal streaming
// avoids L1/L2/L3 allocate+evict churn on 1 GB of touch-once traffic.

constexpr int W = 256;
constexpr int H = 256;
constexpr float F0 = 0.25f;
constexpr float F1 = 0.75f;

typedef float f32x4 __attribute__((ext_vector_type(4)));

// Horizontal 4-tap pass. Lane l holds cols [4l,4l+3]; halo via 3 shuffles.
__device__ __forceinline__ f32x4 hfilt(const f32x4 v, const int lane) {
    float xl2 = __shfl_up(v.z, 1);
    float xl1 = __shfl_up(v.w, 1);
    float xr  = __shfl_down(v.x, 1);
    if (lane == 0)  { xl2 = 0.0f; xl1 = 0.0f; }
    if (lane == 63) { xr = 0.0f; }
    f32x4 h;
    h.x = F0 * xl2 + F1 * xl1 + F1 * v.x + F0 * v.y;
    h.y = F0 * xl1 + F1 * v.x + F1 * v.y + F0 * v.z;
    h.z = F0 * v.x + F1 * v.y + F1 * v.z + F0 * v.w;
    h.w = F0 * v.y + F1 * v.z + F1 * v.w + F0 * xr;
    return h;
}

// Vertical 4-tap: out = F0*(A+D) + F1*(B+C), componentwise.
__device__ __forceinline__ f32x4 vfilt(const f32x4 A, const f32x4 B,
                                       const f32x4 C, const f32x4 D) {
    f32x4 o;
    o.x = F0 * (A.x + D.x) + F1 * (B.x + C.x);
    o.y = F0 * (A.y + D.y) + F1 * (B.y + C.y);
    o.z = F0 * (A.z + D.z) + F1 * (B.z + C.z);
    o.w = F0 * (A.w + D.w) + F1 * (B.w + C.w);
    return o;
}

__global__ __launch_bounds__(256) void blur_kernel(const float* __restrict__ x,
                                                   float* __restrict__ out) {
    const int wave  = threadIdx.x >> 6;
    const int lane  = threadIdx.x & 63;
    const int plane = blockIdx.x * 4 + wave;   // one full plane per wave
    const float* xp = x + (size_t)plane * (H * W);
    float*       op = out + (size_t)plane * (H * W);
    const int col = lane * 4;

    auto loadrow = [&](int i) -> f32x4 {
        if ((unsigned)i >= (unsigned)H) return f32x4{0.f, 0.f, 0.f, 0.f};
        return __builtin_nontemporal_load(
            reinterpret_cast<const f32x4*>(xp + i * W + col));
    };
    auto storerow = [&](int i, const f32x4 o) {
        __builtin_nontemporal_store(o, reinterpret_cast<f32x4*>(op + i * W + col));
    };

    // Rolling window of hfilt'd rows: out io needs h(io-2),h(io-1),h(io),h(io+1).
    f32x4 A = hfilt(loadrow(-2), lane);   // zero rows (no load issued)
    f32x4 B = hfilt(loadrow(-1), lane);
    f32x4 C = hfilt(loadrow(0), lane);

    // Two 4-row raw-input buffers, 8 rows in flight (named: static indexing).
    f32x4 a0 = loadrow(1), a1 = loadrow(2), a2 = loadrow(3), a3 = loadrow(4);
    f32x4 b0 = loadrow(5), b1 = loadrow(6), b2 = loadrow(7), b3 = loadrow(8);

#pragma unroll 2
    for (int g = 0; g < 32; ++g) {
        const int base = 8 * g;        // outputs base..base+7 this group
        const bool refill = (g < 31);

        // ---- half 1: consume a (rows base+1..base+4), outputs base..base+3
        f32x4 D0 = hfilt(a0, lane), D1 = hfilt(a1, lane),
              D2 = hfilt(a2, lane), D3 = hfilt(a3, lane);
        f32x4 o0 = vfilt(A,  B,  C,  D0);
        f32x4 o1 = vfilt(B,  C,  D0, D1);
        f32x4 o2 = vfilt(C,  D0, D1, D2);
        f32x4 o3 = vfilt(D0, D1, D2, D3);
        A = D1; B = D2; C = D3;
        if (refill) {  // rows base+9..base+12 BEFORE the stores
            a0 = loadrow(base + 9);  a1 = loadrow(base + 10);
            a2 = loadrow(base + 11); a3 = loadrow(base + 12);
        }
        storerow(base,     o0); storerow(base + 1, o1);
        storerow(base + 2, o2); storerow(base + 3, o3);

        // ---- half 2: consume b (rows base+5..base+8), outputs base+4..base+7
        f32x4 E0 = hfilt(b0, lane), E1 = hfilt(b1, lane),
              E2 = hfilt(b2, lane), E3 = hfilt(b3, lane);
        f32x4 p0 = vfilt(A,  B,  C,  E0);
        f32x4 p1 = vfilt(B,  C,  E0, E1);
        f32x4 p2 = vfilt(C,  E0, E1, E2);
        f32x4 p3 = vfilt(E0, E1, E2, E3);
        A = E1; B = E2; C = E3;
        if (refill) {  // rows base+13..base+16 BEFORE the stores
            b0 = loadrow(base + 13); b1 = loadrow(base + 14);
            b2 = loadrow(base + 15); b3 = loadrow(base + 16);
        }
        storerow(base + 4, p0); storerow(base + 5, p1);
        storerow(base + 6, p2); storerow(base + 7, p3);
    }
}

extern "C" void kernel_launch(void* const* d_in, const int* in_sizes, int n_in,
                              void* d_out, int out_size, void* d_ws, size_t ws_size,
                              hipStream_t stream) {
    const float* x = (const float*)d_in[0];
    float* o = (float*)d_out;
    const int planes = in_sizes[0] / (H * W);  // N*C = 2048
    blur_kernel<<<planes / 4, 256, 0, stream>>>(x, o);
}